// Round 5
// baseline (465.173 us; speedup 1.0000x reference)
//
#include <hip/hip_runtime.h>

// Problem constants: b=1, m=128, n=256 (positions), c=22 classes
#define NC    22
#define NROW  (NC*NC)        // 484 floats per (i,j) coupling block
#define NJ    256
#define NI    256
#define NM    128
#define JG    8              // j's per superstep
#define NQJ   4              // j-quarters (blockIdx.y) -> 1024 blocks = exactly 4/CU
#define JQ    (NJ/NQJ)       // 64 j's per block
#define SS    (JQ/JG)        // 8 supersteps
#define ROWDW 16             // dwords per (j,c) row: 32 bf16 (d padded 22->32)
#define JROW  (NC*ROWDW)     // 352 dwords per j
#define TILEDW (JG*JROW)     // 2816 dwords per buffer (11264 B)
#define F4PS  (JG*NROW/4)    // 968 float4 staged per superstep
#define SLAB  (NI*NM*NC)     // 720896 floats per j-quarter partial slab
#define NRB   (SLAB/1024)    // 704 reduce blocks

typedef __attribute__((ext_vector_type(8))) short short8;  // bf16x8 A/B frag
typedef __attribute__((ext_vector_type(4))) float f32x4;   // fp32x4 C/D frag

__device__ __forceinline__ uint32_t pk_bf16(float lo, float hi) { // 2xf32 -> packed bf16 (RNE)
    uint32_t r;
    asm("v_cvt_pk_bf16_f32 %0, %1, %2" : "=v"(r) : "v"(lo), "v"(hi));
    return r;
}

// part[jq][i][m][c] = sum_{j in quarter} eij[i,j,c,v[m,j]] * mask_vec[v[m,j]]
// MFMA: hi = A(one-hot over (j,d)) x B(em), K-block = 32 (one j). B-frag reads
// 8 consecutive d's == native eij order -> ds_read_b128, no transpose.
// This round: depth-2 register prefetch (stage(s) consumes loads issued at
// s-2 -> vmcnt stall ~0) and one-time u8 v-table (no per-superstep vtab
// restage in the vmcnt/barrier chain). Geometry unchanged: 4 blocks/CU.
__global__ __launch_bounds__(256) void potts_mfma(
    const int*   __restrict__ variant,   // [128,256] int32
    const float* __restrict__ eij,       // [256,256,22,22]
    const float* __restrict__ mask_vec,  // [22]
    float*       __restrict__ part,      // [4,256,128,22] workspace (11.5 MB)
    unsigned*    __restrict__ sync_cnt)  // 1 dword (for reduce's last-block pool)
{
    const int i    = blockIdx.x;
    const int jq   = blockIdx.y;
    const int tid  = threadIdx.x;
    const int lane = tid & 63;
    const int wv   = tid >> 6;           // wave 0..3
    const int q    = lane >> 4;          // k-quad / row-quad
    const int nl   = lane & 15;          // fragment row/col index

    if (i == 0 && jq == 0 && tid == 0) *sync_cnt = 0;  // un-poison ticket

    __shared__ uint32_t      tile[2][TILEDW]; // bf16 em tiles, 22528 B
    __shared__ unsigned char vt8[JQ][NM];     // v[j][m] u8, staged ONCE, 8192 B
    // total 30720 B -> 4 blocks/CU (123 KB), 16 waves/CU

    // Zero the d-pad (w=11..15 of every (j,c) row) once per buffer; staging
    // never writes there, MFMA reads it as B[k=22..31][*] (junk could be NaN,
    // NaN*0=NaN -> must be 0). Disjoint from staged w=0..10 -> no extra barrier.
    for (int p = tid; p < 2 * JG * NC * 5; p += 256) {
        const int b  = p / (JG * NC * 5), r = p % (JG * NC * 5);
        const int jl = r / (NC * 5),     r2 = r % (NC * 5);
        tile[b][jl * JROW + (r2 / 5) * ROWDW + 11 + r2 % 5] = 0;
    }
    // Whole quarter's variant table -> u8 LDS [j-local][m]. Coalesced reads
    // (64-dword runs per m); loop reads are same-dword broadcasts.
    for (int p = tid; p < JQ * NM; p += 256) {
        const int m = p >> 6, jl = p & 63;
        vt8[jl][m] = (unsigned char)variant[m * NJ + jq * JQ + jl];
    }
    // First use of vt8/pads is after the first __syncthreads in step(). OK.

    // Staging decomposition: float4 f4 = r*256+tid covers 968 float4 = 8 j of
    // 484 floats. 484/4=121 float4/j (no j straddle); each float4 = two
    // float2s, each within one 22-float c-row (22 even). Mask folded here.
    int   l0[4], l1[4];
    float mk[4][4];
    bool  act[4];
    #pragma unroll
    for (int r = 0; r < 4; ++r) {
        const int f4 = r * 256 + tid;
        act[r] = (f4 < F4PS);
        const int fc = act[r] ? f4 : 0;
        const int jl = fc / 121, r4 = fc % 121;
        const int f2a = 2 * r4, f2b = f2a + 1;
        const int ca = f2a / 11, wa = f2a % 11;
        const int cb = f2b / 11, wb = f2b % 11;
        l0[r] = jl * JROW + ca * ROWDW + wa;
        l1[r] = jl * JROW + cb * ROWDW + wb;
        mk[r][0] = mask_vec[2 * wa];  mk[r][1] = mask_vec[2 * wa + 1];
        mk[r][2] = mask_vec[2 * wb];  mk[r][3] = mask_vec[2 * wb + 1];
    }

    const float4* gsrc = (const float4*)eij + (size_t)(i * NJ + jq * JQ) * 121;

    // Wave-constant fragment addresses. nt=1 covers c=16..31; c>=22 lanes are
    // clamped to row 0 (real data, never NaN); their D columns are discarded.
    const int c1   = 16 + nl;
    const int off0 = nl * ROWDW + q * 4;
    const int off1 = (c1 < NC ? c1 : 0) * ROWDW + q * 4;
    const int m0a  = wv * 16;            // m-tiles: wv and wv+4
    const int m0b  = wv * 16 + 64;

    f32x4 acc_a0 = {0.f,0.f,0.f,0.f}, acc_a1 = {0.f,0.f,0.f,0.f};
    f32x4 acc_b0 = {0.f,0.f,0.f,0.f}, acc_b1 = {0.f,0.f,0.f,0.f};

    // Depth-2 prefetch: pfA holds even chunks, pfB odd (named arrays ->
    // static register indexing, no scratch).
    float4 pfA[4], pfB[4];
    #pragma unroll
    for (int r = 0; r < 4; ++r)
        if (act[r]) pfA[r] = gsrc[r * 256 + tid];
    #pragma unroll
    for (int r = 0; r < 4; ++r)
        if (act[r]) pfB[r] = gsrc[(size_t)F4PS + r * 256 + tid];

    // One superstep: stage pf -> tile[bsel] (bf16, mask folded), barrier,
    // reload pf from chunk s+2, compute 8 j's.
    // Buffer-hazard invariant (proven R1): writes to buffer b at superstep s
    // occur after barrier(s-1), which follows all reads of b at s-2 in
    // program order. Register depth doesn't change LDS hazards.
    auto step = [&](float4 (&pf)[4], int bsel, int s) {
        uint32_t* buf = tile[bsel];
        #pragma unroll
        for (int r = 0; r < 4; ++r) {
            if (act[r]) {
                const float4 v = pf[r];
                buf[l0[r]] = pk_bf16(v.x * mk[r][0], v.y * mk[r][1]);
                buf[l1[r]] = pk_bf16(v.z * mk[r][2], v.w * mk[r][3]);
            }
        }
        __syncthreads();
        if (s + 2 < SS) {
            const float4* gn = gsrc + (size_t)(s + 2) * F4PS;
            #pragma unroll
            for (int r = 0; r < 4; ++r)
                if (act[r]) pf[r] = gn[r * 256 + tid];
        }

        // 8 j's: per wave per j: 2 vt8 u8 (broadcast) + 2 B-frag b128
        // (conflict-free: 64 lanes hit 64 distinct aligned 16B chunks) + 4 MFMA
        #pragma unroll
        for (int jl = 0; jl < JG; ++jl) {
            const uint32_t* jrow = buf + jl * JROW;
            const short8 bf0 = *(const short8*)(jrow + off0);
            const short8 bf1 = *(const short8*)(jrow + off1);

            const unsigned char* vrow = vt8[s * JG + jl];
            const int va = vrow[m0a + nl];
            const int vb = vrow[m0b + nl];

            // A-frag: one-hot at d=v within k-quad q. pat = 1.0bf16 in the
            // (v&1) half; placed in dword u iff v>>1 == q*4+u.
            const uint32_t pa = 0x3F80u << ((va & 1) << 4);
            const uint32_t pb = 0x3F80u << ((vb & 1) << 4);
            const int ha = va >> 1, hb = vb >> 1, kb = q * 4;
            union { uint32_t u[4]; short8 s; } fa, fb;
            #pragma unroll
            for (int t = 0; t < 4; ++t) {
                fa.u[t] = (ha == kb + t) ? pa : 0u;
                fb.u[t] = (hb == kb + t) ? pb : 0u;
            }

            acc_a0 = __builtin_amdgcn_mfma_f32_16x16x32_bf16(fa.s, bf0, acc_a0, 0, 0, 0);
            acc_a1 = __builtin_amdgcn_mfma_f32_16x16x32_bf16(fa.s, bf1, acc_a1, 0, 0, 0);
            acc_b0 = __builtin_amdgcn_mfma_f32_16x16x32_bf16(fb.s, bf0, acc_b0, 0, 0, 0);
            acc_b1 = __builtin_amdgcn_mfma_f32_16x16x32_bf16(fb.s, bf1, acc_b1, 0, 0, 0);
        }
    };

    for (int s = 0; s < SS; s += 2) {
        step(pfA, 0, s);
        step(pfB, 1, s + 1);
    }

    // Epilogue: C/D layout col=lane&15, row=(lane>>4)*4+reg (m89-verified).
    float* pbase = part + ((size_t)jq * NI + i) * NM * NC;
    #pragma unroll
    for (int t = 0; t < 4; ++t) {
        const int ra = m0a + q * 4 + t, rb = m0b + q * 4 + t;
        pbase[ra * NC + nl] = acc_a0[t];
        pbase[rb * NC + nl] = acc_b0[t];
        if (c1 < NC) {
            pbase[ra * NC + c1] = acc_a1[t];
            pbase[rb * NC + c1] = acc_b1[t];
        }
    }
}

// motifs[m,i,c] = ei[i,c] + sum_jq part[jq,i,m,c];  logits[m,i]=motifs[m,i,v[m,i]]
// Flat 1-output-per-thread grid: 704*1024 = 720896 = NI*NM*NC exactly; the 4
// partial loads are part[qq*SLAB + idx] -- perfectly coalesced, independent.
// Pool fused via last-block ticket: saves a launch + a 32K-read kernel.
__global__ __launch_bounds__(1024) void potts_reduce(
    const float* __restrict__ part,      // [4,256,128,22]
    const int*   __restrict__ variant,   // [128,256]
    const float* __restrict__ ei,        // [256,22]
    const float* __restrict__ vmask,     // [128,256]
    const float* __restrict__ sigma,     // [1]
    float*       __restrict__ out_motifs,// [128,256,22]
    float*       __restrict__ out_logits,// [128,256]
    float*       __restrict__ out_vl,    // [128]
    unsigned*    __restrict__ sync_cnt)  // zeroed by potts_mfma
{
    const int idx = blockIdx.x * 1024 + threadIdx.x;   // < 720896, no guard
    float s = 0.f;
    #pragma unroll
    for (int qq = 0; qq < NQJ; ++qq)
        s += part[(size_t)qq * SLAB + idx];

    const int i = idx / (NM * NC);       // magic-mul
    const int r = idx - i * (NM * NC);
    const int m = r / NC;
    const int c = r - m * NC;

    const float v = s + ei[i * NC + c];
    out_motifs[((size_t)m * NI + i) * NC + c] = v;
    if (c == variant[m * NJ + i])        // exactly one writer per (m,i)
        out_logits[m * NI + i] = v;

    // ---- last-block pool: vl[m] = sigma * sum_i (lg[m,i]-lg[0,i])*vm[m,i]*vm[0,i]
    __shared__ unsigned ticket;
    __threadfence();                     // release this thread's logit writes
    __syncthreads();                     // all block threads fenced
    if (threadIdx.x == 0) ticket = atomicAdd(sync_cnt, 1u);
    __syncthreads();
    if (ticket == NRB - 1) {             // last block: all logits visible
        __threadfence();                 // acquire
        const int t   = threadIdx.x;     // 128 m x 8 subs
        const int mm  = t >> 3, sub = t & 7;
        float acc = 0.f;
        #pragma unroll 4
        for (int k = 0; k < 32; ++k) {
            const int ii = sub * 32 + k;
            const float vl = out_logits[mm * NI + ii] - out_logits[ii];
            acc += vl * vmask[mm * NI + ii] * vmask[ii];
        }
        acc += __shfl_down(acc, 4, 8);
        acc += __shfl_down(acc, 2, 8);
        acc += __shfl_down(acc, 1, 8);
        if (sub == 0) out_vl[mm] = sigma[0] * acc;
    }
}

extern "C" void kernel_launch(void* const* d_in, const int* in_sizes, int n_in,
                              void* d_out, int out_size, void* d_ws, size_t ws_size,
                              hipStream_t stream) {
    const int*   variant  = (const int*)  d_in[0];  // [1,128,256] int32
    const float* vmask    = (const float*)d_in[1];  // [1,128,256]
    const float* eij      = (const float*)d_in[2];  // [1,256,256,22,22]
    const float* ei       = (const float*)d_in[3];  // [1,256,22]
    const float* mask_vec = (const float*)d_in[4];  // [22]
    const float* sigma    = (const float*)d_in[5];  // [1]

    float* out        = (float*)d_out;
    float* out_motifs = out;                        // 128*256*22
    float* out_logits = out_motifs + NM * NI * NC;  // 128*256
    float* out_vl     = out_logits + NM * NI;       // 128

    float*    part     = (float*)d_ws;              // 4*256*128*22 fl = 11.5 MB
    unsigned* sync_cnt = (unsigned*)(part + (size_t)NQJ * SLAB);

    dim3 gridA(NI, NQJ);
    potts_mfma<<<gridA, 256, 0, stream>>>(variant, eij, mask_vec, part, sync_cnt);
    potts_reduce<<<NRB, 1024, 0, stream>>>(part, variant, ei, vmask, sigma,
                                           out_motifs, out_logits, out_vl,
                                           sync_cnt);
}

// Round 6
// 210.431 us; speedup vs baseline: 2.2106x; 2.2106x over previous
//
#include <hip/hip_runtime.h>

// Problem constants: b=1, m=128, n=256 (positions), c=22 classes
#define NC    22
#define NROW  (NC*NC)        // 484 floats per (i,j) coupling block
#define NJ    256
#define NI    256
#define NM    128
#define NQJ   4              // j-quarters (blockIdx.y) -> 1024 blocks = 4/CU
#define JQ    (NJ/NQJ)       // 64 j's per block (16 per wave)
#define SS    8              // supersteps (2 j per wave per step)
#define ROWDW 16             // dwords per (j,c) row: 32 bf16 (d padded 22->32)
#define JROW  (NC*ROWDW)     // 352 dwords per j
#define WBUF  (2*JROW)       // 704 dwords: one wave's 2-j buffer
#define VTS   132            // padded vt8 row stride (bytes) - kills 64-way bank conflict
#define SLAB  (NI*NM*NC)     // 720896 floats per j-quarter partial slab
#define NRB   (SLAB/1024)    // 704 reduce blocks

typedef __attribute__((ext_vector_type(8))) short short8;  // bf16x8 A/B frag
typedef __attribute__((ext_vector_type(4))) float f32x4;   // fp32x4 C/D frag

__device__ __forceinline__ uint32_t bf16rne(float x) {     // fp32 -> bf16 bits (RNE)
    uint32_t u = __float_as_uint(x);
    u += 0x7FFFu + ((u >> 16) & 1u);
    return u >> 16;
}

__device__ __forceinline__ uint32_t pk_bf16(float lo, float hi) { // 2xf32 -> packed bf16
    uint32_t r;
    asm("v_cvt_pk_bf16_f32 %0, %1, %2" : "=v"(r) : "v"(lo), "v"(hi));
    return r;
}

// part[jq][i][m][c] = sum_{j in quarter} eij[i,j,c,v[m,j]] * mask_vec[v[m,j]]
//
// BARRIER-FREE WAVE-PRIVATE DATAFLOW (R6): each wave owns 16 j's and ALL
// 128 m. It stages its own 2-j tile into its private LDS region (nobody else
// reads it -> no __syncthreads in the main loop; compiler's own-wave
// vmcnt/lgkmcnt ordering suffices), reads each B-frag exactly once (4x less
// LDS read traffic than the m-split layout), and accumulates 8 m-tiles x
// 2 c-tiles (64 VGPR). Mask is folded into A (A[m][d=v] = bf16(mask[v]),
// exact for 0/1 masks) so staging is pure cvt_pk. 16 independent wave
// streams per CU -> no barrier convoys; stalls covered by other waves.
__global__ __launch_bounds__(256, 4) void potts_mfma(
    const int*   __restrict__ variant,   // [128,256] int32
    const float* __restrict__ eij,       // [256,256,22,22]
    const float* __restrict__ mask_vec,  // [22]
    float*       __restrict__ part)      // [4,256,128,22] workspace (11.5 MB)
{
    const int i    = blockIdx.x;
    const int jq   = blockIdx.y;
    const int tid  = threadIdx.x;
    const int lane = tid & 63;
    const int w    = tid >> 6;           // wave 0..3 (owns j-locals w*16..w*16+15)
    const int q    = lane >> 4;          // k-quad / row-quad
    const int nl   = lane & 15;          // fragment row/col index
    const int kb   = q * 4;

    __shared__ uint32_t      tile[4][WBUF * 2];  // per-wave dbuf, 22528 B total
    __shared__ unsigned char vt8[JQ * VTS];      // v[j-local][m], padded rows, 8448 B
    __shared__ uint32_t      patTab[32];         // bf16(mask[v]) pre-shifted to (v&1) half
    // total ~31 KB -> 4 blocks/CU (124 KB), 16 waves/CU

    // ---- one-time init (single barrier) ----
    if (tid < 32) {
        const uint32_t mb = (tid < NC) ? bf16rne(mask_vec[tid]) : 0u;
        patTab[tid] = mb << ((tid & 1) << 4);
    }
    // vt8: coalesced global (lanes jl=0..63 consecutive), bank-spread LDS
    // writes (stride 132B: bank = (jl*33 + m/4) % 32 varies with jl).
    for (int p = tid; p < JQ * NM; p += 256) {
        const int jl = p & 63, m = p >> 6;
        vt8[jl * VTS + m] = (unsigned char)variant[m * NJ + jq * JQ + jl];
    }
    // Zero own region's d-pads (dwords 11..15 of each (j,c) row): A is zero at
    // d>=22 but junk here could be NaN (NaN*0=NaN in MFMA) -> must be 0.
    // Own-wave writes before own-wave reads: program order, no barrier needed.
    {
        uint32_t* wbase = tile[w];
        for (int p = lane; p < 2 * 2 * NC * 5; p += 64) {
            const int b = p / (2 * NC * 5), r = p % (2 * NC * 5);
            const int jl = r / (NC * 5), r2 = r % (NC * 5);
            wbase[b * WBUF + jl * JROW + (r2 / 5) * ROWDW + 11 + r2 % 5] = 0;
        }
    }
    __syncthreads();   // commits vt8 + patTab (pads are wave-local anyway)

    // Staging decomposition: per step this wave loads 2 j x 484 floats =
    // 242 float4 over 64 lanes (r<4, last r partial). float4 F = jl*121+r4
    // covers float2s f2a=2*r4, f2b=f2a+1 of j-local jl; row ca = f2a/11,
    // in-row float2 wa = f2a%11 -> LDS dword jl*352 + ca*16 + wa.
    int  l0[4], l1[4];
    bool act[4];
    #pragma unroll
    for (int r = 0; r < 4; ++r) {
        const int f4 = r * 64 + lane;
        act[r] = (f4 < 242);
        const int fc = act[r] ? f4 : 0;
        const int jl = fc / 121, r4 = fc % 121;
        const int f2a = 2 * r4, f2b = f2a + 1;
        l0[r] = jl * JROW + (f2a / 11) * ROWDW + f2a % 11;
        l1[r] = jl * JROW + (f2b / 11) * ROWDW + f2b % 11;
    }

    // This wave's global source: j's [jq*64 + w*16, +16), 968 floats/step.
    const float4* gsrc = (const float4*)eij
                       + (size_t)(i * NJ + jq * JQ + w * 16) * (NROW / 4);

    // Wave-constant fragment offsets (within a 352-dword j-row). nt=1 covers
    // c=16..31; c>=22 lanes clamp to row 0 (real data, never NaN; D discarded).
    const int c1   = 16 + nl;
    const int off0 = nl * ROWDW + kb;
    const int off1 = (c1 < NC ? c1 : 0) * ROWDW + kb;

    f32x4 acc[8][2];
    #pragma unroll
    for (int t = 0; t < 8; ++t) {
        acc[t][0] = (f32x4){0.f, 0.f, 0.f, 0.f};
        acc[t][1] = (f32x4){0.f, 0.f, 0.f, 0.f};
    }

    // Prologue: issue step-0 loads.
    float4 pf[4];
    #pragma unroll
    for (int r = 0; r < 4; ++r)
        if (act[r]) pf[r] = gsrc[r * 64 + lane];

    for (int s = 0; s < SS; ++s) {
        uint32_t* buf = tile[w] + (s & 1) * WBUF;

        // Stage own 2-j tile as bf16 (no mask mul: folded into A).
        #pragma unroll
        for (int r = 0; r < 4; ++r) {
            if (act[r]) {
                const float4 v = pf[r];
                buf[l0[r]] = pk_bf16(v.x, v.y);
                buf[l1[r]] = pk_bf16(v.z, v.w);
            }
        }
        // Issue next step's loads (WAR on pf resolved by program order);
        // they have the whole compute phase below to land.
        if (s + 1 < SS) {
            const float4* gn = gsrc + (size_t)(s + 1) * 242;
            #pragma unroll
            for (int r = 0; r < 4; ++r)
                if (act[r]) pf[r] = gn[r * 64 + lane];
        }

        // Compute both j's: per j: 2 B-frag b128 (conflict-free: 64 lanes
        // cover 64 distinct aligned 16B chunks) + 8 m-tiles x 2 MFMA.
        #pragma unroll
        for (int jj = 0; jj < 2; ++jj) {
            const uint32_t* jrow = buf + jj * JROW;
            const short8 bf0 = *(const short8*)(jrow + off0);
            const short8 bf1 = *(const short8*)(jrow + off1);

            const unsigned char* vrow = &vt8[(w * 16 + s * 2 + jj) * VTS];
            #pragma unroll
            for (int t = 0; t < 8; ++t) {
                const int      va = vrow[t * 16 + nl];
                const uint32_t pa = patTab[va];   // bf16(mask[va]) in (va&1) half
                const int      ha = va >> 1;
                union { uint32_t u[4]; short8 s; } fa;
                #pragma unroll
                for (int tt = 0; tt < 4; ++tt)
                    fa.u[tt] = (ha == kb + tt) ? pa : 0u;
                acc[t][0] = __builtin_amdgcn_mfma_f32_16x16x32_bf16(fa.s, bf0, acc[t][0], 0, 0, 0);
                acc[t][1] = __builtin_amdgcn_mfma_f32_16x16x32_bf16(fa.s, bf1, acc[t][1], 0, 0, 0);
            }
        }
    }

    // ---- cross-wave j-reduction in LDS (2 barriers), then part store ----
    // red0/red1 = two 128x22 f32 slabs, exactly reusing tile (5632 dw).
    __syncthreads();                     // all waves done with main loop
    float* red   = (float*)&tile[0][0];
    float* myred = red + (w & 1) * (NM * NC);
    // C/D layout (m89-verified): col = lane&15, row = (lane>>4)*4 + reg.
    if (w < 2) {
        #pragma unroll
        for (int t = 0; t < 8; ++t)
            #pragma unroll
            for (int tt = 0; tt < 4; ++tt) {
                const int m = t * 16 + kb + tt;
                myred[m * NC + nl] = acc[t][0][tt];
                if (c1 < NC) myred[m * NC + c1] = acc[t][1][tt];
            }
    }
    __syncthreads();
    if (w >= 2) {                        // disjoint-element RMW, race-free
        #pragma unroll
        for (int t = 0; t < 8; ++t)
            #pragma unroll
            for (int tt = 0; tt < 4; ++tt) {
                const int m = t * 16 + kb + tt;
                myred[m * NC + nl] += acc[t][0][tt];
                if (c1 < NC) myred[m * NC + c1] += acc[t][1][tt];
            }
    }
    __syncthreads();
    float* pbase = part + ((size_t)jq * NI + i) * (NM * NC);
    #pragma unroll
    for (int k = 0; k < 11; ++k) {       // 11*256 = 2816 = NM*NC exactly
        const int p = k * 256 + tid;
        pbase[p] = red[p] + red[NM * NC + p];
    }
}

// motifs[m,i,c] = ei[i,c] + sum_jq part[jq,i,m,c];  logits[m,i]=motifs[m,i,v[m,i]]
// Flat 1-output-per-thread grid: 704*1024 = 720896 = NI*NM*NC exactly; the 4
// partial loads are part[qq*SLAB + idx] -- perfectly coalesced, independent.
__global__ __launch_bounds__(1024) void potts_reduce(
    const float* __restrict__ part,      // [4,256,128,22]
    const int*   __restrict__ variant,   // [128,256]
    const float* __restrict__ ei,        // [256,22]
    float*       __restrict__ out_motifs,// [128,256,22]
    float*       __restrict__ out_logits)// [128,256]
{
    const int idx = blockIdx.x * 1024 + threadIdx.x;   // < 720896, no guard
    float s = 0.f;
    #pragma unroll
    for (int qq = 0; qq < NQJ; ++qq)
        s += part[(size_t)qq * SLAB + idx];

    const int i = idx / (NM * NC);       // magic-mul
    const int r = idx - i * (NM * NC);
    const int m = r / NC;
    const int c = r - m * NC;

    const float v = s + ei[i * NC + c];
    out_motifs[((size_t)m * NI + i) * NC + c] = v;
    if (c == variant[m * NJ + i])        // exactly one writer per (m,i)
        out_logits[m * NI + i] = v;
}

// variant_logit[m] = sigma * sum_i (logits[m,i]-logits[0,i]) * vm[m,i]*vm[0,i]
__global__ __launch_bounds__(64) void potts_pool(
    const float* __restrict__ logits,  // [128,256]
    const float* __restrict__ vmask,   // [128,256]
    const float* __restrict__ sigma,   // [1]
    float*       __restrict__ out_vl)  // [128]
{
    const int m    = blockIdx.x;
    const int lane = threadIdx.x;
    float s = 0.f;
    #pragma unroll
    for (int qq = 0; qq < 4; ++qq) {
        const int i = lane + 64 * qq;
        const float vl = logits[m * NI + i] - logits[i];
        s += vl * vmask[m * NI + i] * vmask[i];
    }
    #pragma unroll
    for (int off = 32; off > 0; off >>= 1)
        s += __shfl_down(s, off, 64);
    if (lane == 0) out_vl[m] = sigma[0] * s;
}

extern "C" void kernel_launch(void* const* d_in, const int* in_sizes, int n_in,
                              void* d_out, int out_size, void* d_ws, size_t ws_size,
                              hipStream_t stream) {
    const int*   variant  = (const int*)  d_in[0];  // [1,128,256] int32
    const float* vmask    = (const float*)d_in[1];  // [1,128,256]
    const float* eij      = (const float*)d_in[2];  // [1,256,256,22,22]
    const float* ei       = (const float*)d_in[3];  // [1,256,22]
    const float* mask_vec = (const float*)d_in[4];  // [22]
    const float* sigma    = (const float*)d_in[5];  // [1]

    float* out        = (float*)d_out;
    float* out_motifs = out;                        // 128*256*22
    float* out_logits = out_motifs + NM * NI * NC;  // 128*256
    float* out_vl     = out_logits + NM * NI;       // 128

    float* part = (float*)d_ws;                     // 4*256*128*22 fl = 11.5 MB

    dim3 gridA(NI, NQJ);
    potts_mfma<<<gridA, 256, 0, stream>>>(variant, eij, mask_vec, part);
    potts_reduce<<<NRB, 1024, 0, stream>>>(part, variant, ei,
                                           out_motifs, out_logits);
    potts_pool<<<NM, 64, 0, stream>>>(out_logits, vmask, sigma, out_vl);
}